// Round 6
// baseline (239.780 us; speedup 1.0000x reference)
//
#include <hip/hip_runtime.h>
#include <hip/hip_bf16.h>
#include <math.h>

#define TN 768   // T = N*M flattened nodes
#define HD 64    // hidden H
#define FF 32    // feature dim
#define OUTD 64  // invariant out
#define LL 2     // layers

typedef short short8 __attribute__((ext_vector_type(8)));
typedef short short4v __attribute__((ext_vector_type(4)));
typedef float f32x4 __attribute__((ext_vector_type(4)));
typedef unsigned int uint4v __attribute__((ext_vector_type(4)));

// fast silu: v_exp_f32 + v_rcp_f32
__device__ __forceinline__ float silu_f(float x) {
    float e = __builtin_amdgcn_exp2f(x * -1.44269504089f);
    return x * __builtin_amdgcn_rcpf(1.0f + e);
}

// split fp32 x into hi + lo bf16 parts (truncation split; residual ~ 2^-17 |x|)
__device__ __forceinline__ void bf16_split(float x, short& hi, short& lo) {
    unsigned int u = __float_as_uint(x);
    unsigned int uh = u & 0xFFFF0000u;
    hi = (short)(uh >> 16);
    float r = x - __uint_as_float(uh);
    lo = (short)(__float_as_uint(r) >> 16);
}

// RNE round-to-bf16, returns the 16-bit pattern
__device__ __forceinline__ unsigned short bf16_rne(float x) {
    unsigned int u = __float_as_uint(x);
    u += 0x7FFFu + ((u >> 16) & 1u);
    return (unsigned short)(u >> 16);
}

// RNE-pack two fp32 into one dword of bf16 (a -> low16, b -> high16).
// Uses v_cvt_pk_bf16_f32 when available, else manual RNE + v_perm.
__device__ __forceinline__ unsigned int pk_bf16(float a, float b) {
#if __has_builtin(__builtin_amdgcn_cvt_pk_bf16_f32)
    auto t = __builtin_amdgcn_cvt_pk_bf16_f32(a, b);
    return __builtin_bit_cast(unsigned int, t);
#else
    unsigned int ua = __float_as_uint(a); ua += 0x7FFFu + ((ua >> 16) & 1u);
    unsigned int ub = __float_as_uint(b); ub += 0x7FFFu + ((ub >> 16) & 1u);
    return __builtin_amdgcn_perm(ub, ua, 0x07060302u);
#endif
}

// sum over the 16 lanes of a DPP row — pure VALU, no DS ops.
__device__ __forceinline__ float row16_sum(float v) {
    int x;
    x = __builtin_amdgcn_update_dpp(0, __float_as_int(v), 0xB1, 0xF, 0xF, true);
    v += __int_as_float(x);
    x = __builtin_amdgcn_update_dpp(0, __float_as_int(v), 0x4E, 0xF, 0xF, true);
    v += __int_as_float(x);
    x = __builtin_amdgcn_update_dpp(0, __float_as_int(v), 0x141, 0xF, 0xF, true);
    v += __int_as_float(x);
    x = __builtin_amdgcn_update_dpp(0, __float_as_int(v), 0x140, 0xF, 0xF, true);
    v += __int_as_float(x);
    return v;
}

// ---------------- K0: embedding + x_vec init + A/Bv for layer 0 ----------------
__global__ void k_embed_pre(const float* __restrict__ pos, const float* __restrict__ feat,
                            const float* __restrict__ w_emb, const float* __restrict__ b_emb,
                            const float* __restrict__ we1, const float* __restrict__ be1,
                            float* __restrict__ h, float* __restrict__ x_vec,
                            float* __restrict__ A, float* __restrict__ Bv) {
    int t = blockIdx.x;
    int j = threadIdx.x;  // 64
    __shared__ float sf[FF];
    __shared__ float sh[HD];
    if (j < FF) sf[j] = feat[t * FF + j];
    __syncthreads();
    float acc = b_emb[j];
#pragma unroll
    for (int f = 0; f < FF; ++f) acc += sf[f] * w_emb[f * HD + j];
    h[t * HD + j] = acc;
    sh[j] = acc;
    if (j < 6) x_vec[t * 6 + j] = pos[t * 3 + (j % 3)];
    __syncthreads();
    float a = be1[j], b = 0.f;
#pragma unroll
    for (int i = 0; i < HD; ++i) {
        a += sh[i] * we1[i * HD + j];
        b += sh[i] * we1[(HD + i) * HD + j];
    }
    A[t * HD + j] = a;
    Bv[t * HD + j] = b;
}

// ---------------- K1: fused edge + node-update kernel, one block per receiver ----------------
// 4 waves/block; wave wv owns rows [16wv,16wv+16). Lane = (q=lane>>4, m=lane&15).
// A-frag (16x16x32): A[m][k=q*8+j]; B-frag: B[k=q*8+j][n=m]; C/D: col=m, row=q*4+reg.
// GEMM1 (2-term: RNE-A x (W2h+W2l)): M2pre = M1 @ We2.
// GEMM2 (1-term):                    Ppre  = bf16(M2) @ bf16(Wx1).
// Register-resident weight frags; prefetched sender loads; DPP reductions.
#define SM2S 68  // sM2 row stride in halves
__global__ __launch_bounds__(256, 1) void k_edge(
    const float* __restrict__ xv_in, const float* __restrict__ A_in,
    const float* __restrict__ Bv_in, const float* __restrict__ we1,
    const float* __restrict__ we2, const float* __restrict__ be2,
    const float* __restrict__ wx1, const float* __restrict__ bx1,
    const float* __restrict__ wx2,
    const float* __restrict__ wh1, const float* __restrict__ bh1,
    const float* __restrict__ wh2, const float* __restrict__ bh2,
    const float* __restrict__ be1,
    float* __restrict__ h, float* __restrict__ xv_out,
    float* __restrict__ A_out, float* __restrict__ Bv_out,
    const float* __restrict__ pos, const float* __restrict__ w_head,
    const float* __restrict__ b_head, float* __restrict__ out,
    int l, int last)
{
    const int r = blockIdx.x;
    const int tid = threadIdx.x;
    const int wv = tid >> 6;
    const int lane = tid & 63;
    const int q = lane >> 4;
    const int m = lane & 15;

    __shared__ __align__(16) union USm {
        struct {  // one-time weight staging (transposed [n][k], stride 72)
            unsigned short W2h[64 * 72], W2l[64 * 72], W3h[64 * 72];
        } stg;
        struct {  // loop + tail working set (overlays staging after frag load)
            unsigned short M2[64 * SM2S];  // bf16 M2 [row][col]
            float Phi[64][2];
            float Agg[4][64];
            float XupW[4][8];
            float hr[64], aggF[64], su[64], h2[64];
        } run;
    } u;
    __shared__ __align__(16) float sBvr[64];  // live across loop (outside union)
    __shared__ __align__(16) float sC0[64];
    __shared__ __align__(16) float sC1[64];

    // ---- stage We2 hi/lo + Wx1 (RNE) into LDS transposed, then pull B-frags to REGISTERS ----
    const float* w2 = we2 + (size_t)l * HD * HD;
    const float* w3 = wx1 + (size_t)l * HD * HD;
    for (int e = tid; e < HD * HD; e += 256) {
        int k = e >> 6, n = e & 63;
        short h16, l16;
        bf16_split(w2[e], h16, l16);
        u.stg.W2h[n * 72 + k] = (unsigned short)h16;
        u.stg.W2l[n * 72 + k] = (unsigned short)l16;
        u.stg.W3h[n * 72 + k] = bf16_rne(w3[e]);
    }
    if (tid < HD) {
        sBvr[tid] = Bv_in[r * HD + tid];
        sC0[tid] = we1[((size_t)l * 130 + 128) * HD + tid];
        sC1[tid] = we1[((size_t)l * 130 + 129) * HD + tid];
    }
    __syncthreads();
    short8 bW2h[4][2], bW2l[4][2], bW3h[4][2];
#pragma unroll
    for (int nt = 0; nt < 4; ++nt)
#pragma unroll
        for (int kt = 0; kt < 2; ++kt) {
            int idx = (nt * 16 + m) * 72 + kt * 32 + 8 * q;
            bW2h[nt][kt] = *(const short8*)&u.stg.W2h[idx];
            bW2l[nt][kt] = *(const short8*)&u.stg.W2l[idx];
            bW3h[nt][kt] = *(const short8*)&u.stg.W3h[idx];
        }
    __syncthreads();  // staging dead; run region live from here

    // per-lane column constants (col = nt*16+m)
    float be2v[4], bx1v[4], w20[4], w21[4];
#pragma unroll
    for (int nt = 0; nt < 4; ++nt) {
        int col = nt * 16 + m;
        be2v[nt] = be2[l * HD + col];
        bx1v[nt] = bx1[l * HD + col];
        w20[nt] = wx2[((size_t)l * HD + col) * 2 + 0];
        w21[nt] = wx2[((size_t)l * HD + col) * 2 + 1];
    }
    float xr[6];
#pragma unroll
    for (int c = 0; c < 6; ++c) xr[c] = xv_in[r * 6 + c];

    float aggP[4] = {0.f, 0.f, 0.f, 0.f};
    float accX[6] = {0.f, 0.f, 0.f, 0.f, 0.f, 0.f};

    const int rowA = 16 * wv + m;
    // prefetch ping-pong buffers (registers)
    float2 pbuf[2][3];
    float4 abuf[2][2][2];
    {
        int sA = rowA;
        pbuf[0][0] = *(const float2*)&xv_in[sA * 6 + 0];
        pbuf[0][1] = *(const float2*)&xv_in[sA * 6 + 2];
        pbuf[0][2] = *(const float2*)&xv_in[sA * 6 + 4];
#pragma unroll
        for (int kt = 0; kt < 2; ++kt) {
            abuf[0][kt][0] = *(const float4*)&A_in[sA * HD + kt * 32 + 8 * q];
            abuf[0][kt][1] = *(const float4*)&A_in[sA * HD + kt * 32 + 8 * q + 4];
        }
    }

#pragma unroll 2
    for (int it = 0; it < TN / 64; ++it) {
        const int s0 = it * 64;
        const int pb = it & 1;
        // ---- prefetch next batch into the other buffer ----
        {
            int sN = (s0 + 64 < TN ? s0 + 64 : 0) + rowA;
            pbuf[pb ^ 1][0] = *(const float2*)&xv_in[sN * 6 + 0];
            pbuf[pb ^ 1][1] = *(const float2*)&xv_in[sN * 6 + 2];
            pbuf[pb ^ 1][2] = *(const float2*)&xv_in[sN * 6 + 4];
#pragma unroll
            for (int kt = 0; kt < 2; ++kt) {
                abuf[pb ^ 1][kt][0] = *(const float4*)&A_in[sN * HD + kt * 32 + 8 * q];
                abuf[pb ^ 1][kt][1] = *(const float4*)&A_in[sN * HD + kt * 32 + 8 * q + 4];
            }
        }
        // ---- phase A: diff/sqnorm + M1 A-frags (RNE bf16) ----
        float2 p01 = pbuf[pb][0], p23 = pbuf[pb][1], p45 = pbuf[pb][2];
        float d0 = p01.x - xr[0], d1 = p01.y - xr[1], d2 = p23.x - xr[2];
        float d3 = p23.y - xr[3], d4 = p45.x - xr[4], d5 = p45.y - xr[5];
        float q0 = d0 * d0 + d1 * d1 + d2 * d2;
        float q1 = d3 * d3 + d4 * d4 + d5 * d5;
        float ik0 = __builtin_amdgcn_rcpf(__builtin_amdgcn_sqrtf(q0 + 1e-8f) + 1.f);
        float ik1 = __builtin_amdgcn_rcpf(__builtin_amdgcn_sqrtf(q1 + 1e-8f) + 1.f);

        short8 a1h[2];
#pragma unroll
        for (int kt = 0; kt < 2; ++kt) {
            int jb = kt * 32 + 8 * q;
            float av[8], bb[8], c0[8], c1[8];
            *(float4*)&av[0] = abuf[pb][kt][0];
            *(float4*)&av[4] = abuf[pb][kt][1];
            *(float4*)&bb[0] = *(const float4*)&sBvr[jb];
            *(float4*)&bb[4] = *(const float4*)&sBvr[jb + 4];
            *(float4*)&c0[0] = *(const float4*)&sC0[jb];
            *(float4*)&c0[4] = *(const float4*)&sC0[jb + 4];
            *(float4*)&c1[0] = *(const float4*)&sC1[jb];
            *(float4*)&c1[4] = *(const float4*)&sC1[jb + 4];
            float mv[8];
#pragma unroll
            for (int jj = 0; jj < 8; ++jj) {
                float pre = av[jj] + bb[jj] + q0 * c0[jj] + q1 * c1[jj];
                mv[jj] = silu_f(pre);
            }
            uint4v uh;
            unsigned int* uhp = (unsigned int*)&uh;
#pragma unroll
            for (int jp = 0; jp < 4; ++jp)
                uhp[jp] = pk_bf16(mv[2 * jp], mv[2 * jp + 1]);
            a1h[kt] = __builtin_bit_cast(short8, uh);
        }

        // ---- phase B: M2pre = M1 @ We2 (2-term: A-RNE x (W2h+W2l)) ----
        const int rl = r - s0;  // local self row (if in [0,64))
        const bool selfw = (rl >= 16 * wv) && (rl < 16 * wv + 16);  // wave-uniform
#pragma unroll
        for (int nt = 0; nt < 4; ++nt) {
            f32x4 acc = {0.f, 0.f, 0.f, 0.f};
#pragma unroll
            for (int kt = 0; kt < 2; ++kt) {
                acc = __builtin_amdgcn_mfma_f32_16x16x32_bf16(a1h[kt], bW2h[nt][kt], acc, 0, 0, 0);
                acc = __builtin_amdgcn_mfma_f32_16x16x32_bf16(a1h[kt], bW2l[nt][kt], acc, 0, 0, 0);
            }
            float vv[4];
#pragma unroll
            for (int reg = 0; reg < 4; ++reg) vv[reg] = silu_f(acc[reg] + be2v[nt]);
            const int il0 = 16 * wv + 4 * q;
            if (__builtin_expect(selfw, 0)) {
                // self row: mask only the agg contribution (phi x diff=0 kills the rest)
#pragma unroll
                for (int reg = 0; reg < 4; ++reg)
                    aggP[nt] += (il0 + reg == rl) ? 0.f : vv[reg];
            } else {
#pragma unroll
                for (int reg = 0; reg < 4; ++reg) aggP[nt] += vv[reg];
            }
            const int col = nt * 16 + m;
            unsigned int pA = pk_bf16(vv[0], vv[1]);
            unsigned int pB = pk_bf16(vv[2], vv[3]);
            u.run.M2[(il0 + 0) * SM2S + col] = (unsigned short)pA;
            u.run.M2[(il0 + 1) * SM2S + col] = (unsigned short)(pA >> 16);
            u.run.M2[(il0 + 2) * SM2S + col] = (unsigned short)pB;
            u.run.M2[(il0 + 3) * SM2S + col] = (unsigned short)(pB >> 16);
        }

        // ---- phase C: Ppre = bf16(M2) @ bf16(Wx1); phi = silu(P)@wx2 ----
        short8 a2h[2];
#pragma unroll
        for (int kt = 0; kt < 2; ++kt) {
            int base = rowA * SM2S + kt * 32 + 8 * q;
            short4v lo = *(const short4v*)&u.run.M2[base];
            short4v hi = *(const short4v*)&u.run.M2[base + 4];
            short8 a2;
#pragma unroll
            for (int jj = 0; jj < 4; ++jj) { a2[jj] = lo[jj]; a2[4 + jj] = hi[jj]; }
            a2h[kt] = a2;
        }
        float phiP[4][2] = {};
#pragma unroll
        for (int nt = 0; nt < 4; ++nt) {
            f32x4 acc = {0.f, 0.f, 0.f, 0.f};
#pragma unroll
            for (int kt = 0; kt < 2; ++kt)
                acc = __builtin_amdgcn_mfma_f32_16x16x32_bf16(a2h[kt], bW3h[nt][kt], acc, 0, 0, 0);
#pragma unroll
            for (int reg = 0; reg < 4; ++reg) {
                float p = silu_f(acc[reg] + bx1v[nt]);
                phiP[reg][0] += p * w20[nt];
                phiP[reg][1] += p * w21[nt];
            }
        }
#pragma unroll
        for (int reg = 0; reg < 4; ++reg) {
            phiP[reg][0] = row16_sum(phiP[reg][0]);
            phiP[reg][1] = row16_sum(phiP[reg][1]);
        }
        if (m == 0) {
#pragma unroll
            for (int reg = 0; reg < 4; ++reg) {
                int il = 16 * wv + 4 * q + reg;
                *(float2*)&u.run.Phi[il][0] = make_float2(phiP[reg][0], phiP[reg][1]);
            }
        }
        if (q == 0) {
            float2 ph = *(const float2*)&u.run.Phi[rowA][0];
            float f0 = ph.x * ik0;
            float f1 = ph.y * ik1;
            accX[0] += f0 * d0; accX[1] += f0 * d1; accX[2] += f0 * d2;
            accX[3] += f1 * d3; accX[4] += f1 * d4; accX[5] += f1 * d5;
        }
    }

    // ---- final reductions: aggP cross-row shfl; accX DPP row-sum ----
#pragma unroll
    for (int nt = 0; nt < 4; ++nt) {
        aggP[nt] += __shfl_xor(aggP[nt], 16, 64);
        aggP[nt] += __shfl_xor(aggP[nt], 32, 64);
    }
#pragma unroll
    for (int c = 0; c < 6; ++c) accX[c] = row16_sum(accX[c]);
    if (q == 0) {
#pragma unroll
        for (int nt = 0; nt < 4; ++nt) u.run.Agg[wv][nt * 16 + m] = aggP[nt];
        if (m == 0) {
#pragma unroll
            for (int c = 0; c < 6; ++c) u.run.XupW[wv][c] = accX[c];
        }
    }
    __syncthreads();

    // ---- fused node update tail ----
    float xup = 0.f;
    if (tid < 64) {
        u.run.aggF[tid] = u.run.Agg[0][tid] + u.run.Agg[1][tid] +
                          u.run.Agg[2][tid] + u.run.Agg[3][tid];
        u.run.hr[tid] = h[r * HD + tid];
    }
    __syncthreads();
    if (tid < 64) {
        int j = tid;
        const float* w1 = wh1 + (size_t)l * 128 * HD;
        float acc = bh1[l * HD + j];
#pragma unroll
        for (int i = 0; i < HD; ++i) acc += u.run.hr[i] * w1[i * HD + j];
#pragma unroll
        for (int i = 0; i < HD; ++i) acc += u.run.aggF[i] * w1[(HD + i) * HD + j];
        u.run.su[j] = silu_f(acc);
    }
    __syncthreads();
    if (tid < 64) {
        int j = tid;
        const float* wq = wh2 + (size_t)l * HD * HD;
        float v = 0.f;
#pragma unroll
        for (int i = 0; i < HD; ++i) v += u.run.su[i] * wq[i * HD + j];
        float hn = u.run.hr[j] + v + bh2[l * HD + j];
        h[r * HD + j] = hn;
        u.run.h2[j] = hn;
    }
    if (tid < 6) {
        xup = u.run.XupW[0][tid] + u.run.XupW[1][tid] +
              u.run.XupW[2][tid] + u.run.XupW[3][tid];
    }
    __syncthreads();
    if (!last) {
        if (tid < 64) {
            int j = tid;
            const float* w = we1 + (size_t)(l + 1) * 130 * HD;
            float a = be1[(l + 1) * HD + j], b = 0.f;
#pragma unroll
            for (int i = 0; i < HD; ++i) {
                a += u.run.h2[i] * w[i * HD + j];
                b += u.run.h2[i] * w[(HD + i) * HD + j];
            }
            A_out[r * HD + j] = a;
            Bv_out[r * HD + j] = b;
        }
        if (tid < 6) {
            xv_out[r * 6 + tid] = xr[tid] + xup * (1.0f / 767.0f);
        }
    } else {
        if (tid < 64) {
            int j = tid;
            float o = b_head[j];
#pragma unroll
            for (int i = 0; i < HD; ++i) o += u.run.h2[i] * w_head[i * OUTD + j];
            out[TN * 6 + r * OUTD + j] = o;
        }
        if (tid < 6) {
            float xv = xr[tid] + xup * (1.0f / 767.0f);
            out[r * 6 + tid] = xv - pos[r * 3 + (tid % 3)];
        }
    }
}

extern "C" void kernel_launch(void* const* d_in, const int* in_sizes, int n_in,
                              void* d_out, int out_size, void* d_ws, size_t ws_size,
                              hipStream_t stream)
{
    const float* pos    = (const float*)d_in[0];
    const float* feat   = (const float*)d_in[1];
    const float* w_emb  = (const float*)d_in[2];
    const float* b_emb  = (const float*)d_in[3];
    const float* we1    = (const float*)d_in[4];
    const float* be1    = (const float*)d_in[5];
    const float* we2    = (const float*)d_in[6];
    const float* be2    = (const float*)d_in[7];
    const float* wx1    = (const float*)d_in[8];
    const float* bx1    = (const float*)d_in[9];
    const float* wx2    = (const float*)d_in[10];
    const float* wh1    = (const float*)d_in[11];
    const float* bh1    = (const float*)d_in[12];
    const float* wh2    = (const float*)d_in[13];
    const float* bh2    = (const float*)d_in[14];
    const float* w_head = (const float*)d_in[15];
    const float* b_head = (const float*)d_in[16];
    float* out = (float*)d_out;

    float* ws   = (float*)d_ws;
    float* h    = ws;                  // TN*HD
    float* xv0  = h + TN * HD;         // TN*6
    float* xv1  = xv0 + TN * 6;        // TN*6
    float* A0   = xv1 + TN * 6;        // TN*HD
    float* A1   = A0 + TN * HD;        // TN*HD
    float* Bv0  = A1 + TN * HD;        // TN*HD
    float* Bv1  = Bv0 + TN * HD;       // TN*HD

    k_embed_pre<<<TN, 64, 0, stream>>>(pos, feat, w_emb, b_emb, we1, be1,
                                       h, xv0, A0, Bv0);
    k_edge<<<TN, 256, 0, stream>>>(xv0, A0, Bv0, we1, we2, be2, wx1, bx1, wx2,
                                   wh1, bh1, wh2, bh2, be1,
                                   h, xv1, A1, Bv1,
                                   pos, w_head, b_head, out, 0, 0);
    k_edge<<<TN, 256, 0, stream>>>(xv1, A1, Bv1, we1, we2, be2, wx1, bx1, wx2,
                                   wh1, bh1, wh2, bh2, be1,
                                   h, xv0, A0, Bv0,
                                   pos, w_head, b_head, out, 1, 1);
}

// Round 7
// 210.501 us; speedup vs baseline: 1.1391x; 1.1391x over previous
//
#include <hip/hip_runtime.h>
#include <math.h>

#define TN 768   // T = N*M flattened nodes
#define HD 64    // hidden H
#define FF 32    // feature dim
#define OUTD 64  // invariant out
#define LL 2     // layers

typedef short short8 __attribute__((ext_vector_type(8)));
typedef short short4v __attribute__((ext_vector_type(4)));
typedef float f32x4 __attribute__((ext_vector_type(4)));
typedef unsigned int uint4v __attribute__((ext_vector_type(4)));

// fast silu: v_exp_f32 + v_rcp_f32
__device__ __forceinline__ float silu_f(float x) {
    float e = __builtin_amdgcn_exp2f(x * -1.44269504089f);
    return x * __builtin_amdgcn_rcpf(1.0f + e);
}

// split fp32 x into hi + lo bf16 parts (truncation split; residual ~ 2^-17 |x|)
__device__ __forceinline__ void bf16_split(float x, short& hi, short& lo) {
    unsigned int u = __float_as_uint(x);
    unsigned int uh = u & 0xFFFF0000u;
    hi = (short)(uh >> 16);
    float r = x - __uint_as_float(uh);
    lo = (short)(__float_as_uint(r) >> 16);
}

// RNE round-to-bf16, returns the 16-bit pattern
__device__ __forceinline__ unsigned short bf16_rne(float x) {
    unsigned int u = __float_as_uint(x);
    u += 0x7FFFu + ((u >> 16) & 1u);
    return (unsigned short)(u >> 16);
}

// RNE-pack two fp32 into one dword of bf16 (a -> low16, b -> high16)
__device__ __forceinline__ unsigned int pk_bf16(float a, float b) {
#if __has_builtin(__builtin_amdgcn_cvt_pk_bf16_f32)
    auto t = __builtin_amdgcn_cvt_pk_bf16_f32(a, b);
    return __builtin_bit_cast(unsigned int, t);
#else
    unsigned int ua = __float_as_uint(a); ua += 0x7FFFu + ((ua >> 16) & 1u);
    unsigned int ub = __float_as_uint(b); ub += 0x7FFFu + ((ub >> 16) & 1u);
    return __builtin_amdgcn_perm(ub, ua, 0x07060302u);
#endif
}

// sum over the 16 lanes of a DPP row — pure VALU, no DS ops.
__device__ __forceinline__ float row16_sum(float v) {
    int x;
    x = __builtin_amdgcn_update_dpp(0, __float_as_int(v), 0xB1, 0xF, 0xF, true);
    v += __int_as_float(x);
    x = __builtin_amdgcn_update_dpp(0, __float_as_int(v), 0x4E, 0xF, 0xF, true);
    v += __int_as_float(x);
    x = __builtin_amdgcn_update_dpp(0, __float_as_int(v), 0x141, 0xF, 0xF, true);
    v += __int_as_float(x);
    x = __builtin_amdgcn_update_dpp(0, __float_as_int(v), 0x140, 0xF, 0xF, true);
    v += __int_as_float(x);
    return v;
}

// ---------------- K0: embedding + x_vec init + A/Bv for layer 0 ----------------
__global__ void k_embed_pre(const float* __restrict__ pos, const float* __restrict__ feat,
                            const float* __restrict__ w_emb, const float* __restrict__ b_emb,
                            const float* __restrict__ we1, const float* __restrict__ be1,
                            float* __restrict__ h, float* __restrict__ x_vec,
                            float* __restrict__ A, float* __restrict__ Bv) {
    int t = blockIdx.x;
    int j = threadIdx.x;  // 64
    __shared__ float sf[FF];
    __shared__ float sh[HD];
    if (j < FF) sf[j] = feat[t * FF + j];
    __syncthreads();
    float acc = b_emb[j];
#pragma unroll
    for (int f = 0; f < FF; ++f) acc += sf[f] * w_emb[f * HD + j];
    h[t * HD + j] = acc;
    sh[j] = acc;
    if (j < 6) x_vec[t * 6 + j] = pos[t * 3 + (j % 3)];
    __syncthreads();
    float a = be1[j], b = 0.f;
#pragma unroll
    for (int i = 0; i < HD; ++i) {
        a += sh[i] * we1[i * HD + j];
        b += sh[i] * we1[(HD + i) * HD + j];
    }
    A[t * HD + j] = a;
    Bv[t * HD + j] = b;
}

// ---------------- K1: fused edge + node-update kernel, one block per receiver ----------------
// 4 waves/block; wave wv owns rows [16wv,16wv+16). Lane = (q=lane>>4, m=lane&15).
// A-frag (16x16x32): A[m][k=q*8+j]; B-frag: B[k=q*8+j][n=m]; C/D: col=m, row=q*4+reg.
// GEMM1 (2-term: RNE-A x (W2h+W2l)): M2pre = M1 @ We2.
// GEMM2 (1-term):                    Ppre  = bf16(M2) @ bf16(Wx1).
// Register weight frags + register batch-invariant consts; DPP reductions; unroll 1.
#define SM2S 68  // sM2 row stride in halves
__global__ __launch_bounds__(256, 1) void k_edge(
    const float* __restrict__ xv_in, const float* __restrict__ A_in,
    const float* __restrict__ Bv_in, const float* __restrict__ we1,
    const float* __restrict__ we2, const float* __restrict__ be2,
    const float* __restrict__ wx1, const float* __restrict__ bx1,
    const float* __restrict__ wx2,
    const float* __restrict__ wh1, const float* __restrict__ bh1,
    const float* __restrict__ wh2, const float* __restrict__ bh2,
    const float* __restrict__ be1,
    float* __restrict__ h, float* __restrict__ xv_out,
    float* __restrict__ A_out, float* __restrict__ Bv_out,
    const float* __restrict__ pos, const float* __restrict__ w_head,
    const float* __restrict__ b_head, float* __restrict__ out,
    int l, int last)
{
    const int r = blockIdx.x;
    const int tid = threadIdx.x;
    const int wv = tid >> 6;
    const int lane = tid & 63;
    const int q = lane >> 4;
    const int m = lane & 15;

    __shared__ __align__(16) union USm {
        struct {  // one-time weight staging (transposed [n][k], stride 72)
            unsigned short W2h[64 * 72], W2l[64 * 72], W3h[64 * 72];
        } stg;
        struct {  // loop + tail working set (overlays staging after frag load)
            unsigned short M2[64 * SM2S];  // bf16 M2 [row][col]
            float Phi[64][2];
            float Agg[4][64];
            float XupW[4][8];
            float hr[64], aggF[64], su[64], h2[64];
        } run;
    } u;

    // ---- stage We2 hi/lo + Wx1 (RNE) into LDS transposed, then pull B-frags to REGISTERS ----
    const float* w2 = we2 + (size_t)l * HD * HD;
    const float* w3 = wx1 + (size_t)l * HD * HD;
    for (int e = tid; e < HD * HD; e += 256) {
        int k = e >> 6, n = e & 63;
        short h16, l16;
        bf16_split(w2[e], h16, l16);
        u.stg.W2h[n * 72 + k] = (unsigned short)h16;
        u.stg.W2l[n * 72 + k] = (unsigned short)l16;
        u.stg.W3h[n * 72 + k] = bf16_rne(w3[e]);
    }
    __syncthreads();
    short8 bW2h[4][2], bW2l[4][2], bW3h[4][2];
#pragma unroll
    for (int nt = 0; nt < 4; ++nt)
#pragma unroll
        for (int kt = 0; kt < 2; ++kt) {
            int idx = (nt * 16 + m) * 72 + kt * 32 + 8 * q;
            bW2h[nt][kt] = *(const short8*)&u.stg.W2h[idx];
            bW2l[nt][kt] = *(const short8*)&u.stg.W2l[idx];
            bW3h[nt][kt] = *(const short8*)&u.stg.W3h[idx];
        }
    __syncthreads();  // staging dead; run region live from here

    // ---- batch-invariant per-lane constants in REGISTERS ----
    float bbA[2][8], c0A[2][8], c1A[2][8];
#pragma unroll
    for (int kt = 0; kt < 2; ++kt) {
        int jb = kt * 32 + 8 * q;
        *(float4*)&bbA[kt][0] = *(const float4*)&Bv_in[r * HD + jb];
        *(float4*)&bbA[kt][4] = *(const float4*)&Bv_in[r * HD + jb + 4];
        *(float4*)&c0A[kt][0] = *(const float4*)&we1[((size_t)l * 130 + 128) * HD + jb];
        *(float4*)&c0A[kt][4] = *(const float4*)&we1[((size_t)l * 130 + 128) * HD + jb + 4];
        *(float4*)&c1A[kt][0] = *(const float4*)&we1[((size_t)l * 130 + 129) * HD + jb];
        *(float4*)&c1A[kt][4] = *(const float4*)&we1[((size_t)l * 130 + 129) * HD + jb + 4];
    }
    float be2v[4], bx1v[4], w20[4], w21[4];
#pragma unroll
    for (int nt = 0; nt < 4; ++nt) {
        int col = nt * 16 + m;
        be2v[nt] = be2[l * HD + col];
        bx1v[nt] = bx1[l * HD + col];
        w20[nt] = wx2[((size_t)l * HD + col) * 2 + 0];
        w21[nt] = wx2[((size_t)l * HD + col) * 2 + 1];
    }
    float xr[6];
#pragma unroll
    for (int c = 0; c < 6; ++c) xr[c] = xv_in[r * 6 + c];

    float aggP[4] = {0.f, 0.f, 0.f, 0.f};
    float accX[6] = {0.f, 0.f, 0.f, 0.f, 0.f, 0.f};
    const int rowA = 16 * wv + m;

#pragma unroll 1
    for (int s0 = 0; s0 < TN; s0 += 64) {
        // ---- phase A: row sA = s0 + rowA; M1 A-frags (RNE bf16) in registers ----
        const int sA = s0 + rowA;
        float2 p01 = *(const float2*)&xv_in[sA * 6 + 0];
        float2 p23 = *(const float2*)&xv_in[sA * 6 + 2];
        float2 p45 = *(const float2*)&xv_in[sA * 6 + 4];
        float d0 = p01.x - xr[0], d1 = p01.y - xr[1], d2 = p23.x - xr[2];
        float d3 = p23.y - xr[3], d4 = p45.x - xr[4], d5 = p45.y - xr[5];
        float q0 = d0 * d0 + d1 * d1 + d2 * d2;
        float q1 = d3 * d3 + d4 * d4 + d5 * d5;
        float ik0 = __builtin_amdgcn_rcpf(__builtin_amdgcn_sqrtf(q0 + 1e-8f) + 1.f);
        float ik1 = __builtin_amdgcn_rcpf(__builtin_amdgcn_sqrtf(q1 + 1e-8f) + 1.f);

        short8 a1h[2];
#pragma unroll
        for (int kt = 0; kt < 2; ++kt) {
            int jb = kt * 32 + 8 * q;
            float av[8];
            *(float4*)&av[0] = *(const float4*)&A_in[sA * HD + jb];
            *(float4*)&av[4] = *(const float4*)&A_in[sA * HD + jb + 4];
            float mv[8];
#pragma unroll
            for (int jj = 0; jj < 8; ++jj) {
                float pre = av[jj] + bbA[kt][jj] + q0 * c0A[kt][jj] + q1 * c1A[kt][jj];
                mv[jj] = silu_f(pre);
            }
            uint4v uh;
            unsigned int* uhp = (unsigned int*)&uh;
#pragma unroll
            for (int jp = 0; jp < 4; ++jp)
                uhp[jp] = pk_bf16(mv[2 * jp], mv[2 * jp + 1]);
            a1h[kt] = __builtin_bit_cast(short8, uh);
        }

        // ---- phase B: M2pre = M1 @ We2 (2-term: A-RNE x (W2h+W2l)) ----
        const int rl = r - s0;  // local self row (if in [0,64))
        const bool selfw = (rl >= 16 * wv) && (rl < 16 * wv + 16);  // wave-uniform
#pragma unroll
        for (int nt = 0; nt < 4; ++nt) {
            f32x4 acc = {0.f, 0.f, 0.f, 0.f};
#pragma unroll
            for (int kt = 0; kt < 2; ++kt) {
                acc = __builtin_amdgcn_mfma_f32_16x16x32_bf16(a1h[kt], bW2h[nt][kt], acc, 0, 0, 0);
                acc = __builtin_amdgcn_mfma_f32_16x16x32_bf16(a1h[kt], bW2l[nt][kt], acc, 0, 0, 0);
            }
            float vv[4];
#pragma unroll
            for (int reg = 0; reg < 4; ++reg) vv[reg] = silu_f(acc[reg] + be2v[nt]);
            const int il0 = 16 * wv + 4 * q;
            if (__builtin_expect(selfw, 0)) {
                // self row: mask only the agg contribution (phi x diff=0 kills the rest)
#pragma unroll
                for (int reg = 0; reg < 4; ++reg)
                    aggP[nt] += (il0 + reg == rl) ? 0.f : vv[reg];
            } else {
#pragma unroll
                for (int reg = 0; reg < 4; ++reg) aggP[nt] += vv[reg];
            }
            const int col = nt * 16 + m;
            unsigned int pA = pk_bf16(vv[0], vv[1]);
            unsigned int pB = pk_bf16(vv[2], vv[3]);
            u.run.M2[(il0 + 0) * SM2S + col] = (unsigned short)pA;
            u.run.M2[(il0 + 1) * SM2S + col] = (unsigned short)(pA >> 16);
            u.run.M2[(il0 + 2) * SM2S + col] = (unsigned short)pB;
            u.run.M2[(il0 + 3) * SM2S + col] = (unsigned short)(pB >> 16);
        }

        // ---- phase C: Ppre = bf16(M2) @ bf16(Wx1); phi = silu(P)@wx2 ----
        short8 a2h[2];
#pragma unroll
        for (int kt = 0; kt < 2; ++kt) {
            int base = rowA * SM2S + kt * 32 + 8 * q;
            short4v lo = *(const short4v*)&u.run.M2[base];
            short4v hi = *(const short4v*)&u.run.M2[base + 4];
            short8 a2;
#pragma unroll
            for (int jj = 0; jj < 4; ++jj) { a2[jj] = lo[jj]; a2[4 + jj] = hi[jj]; }
            a2h[kt] = a2;
        }
        float phiP[4][2] = {};
#pragma unroll
        for (int nt = 0; nt < 4; ++nt) {
            f32x4 acc = {0.f, 0.f, 0.f, 0.f};
#pragma unroll
            for (int kt = 0; kt < 2; ++kt)
                acc = __builtin_amdgcn_mfma_f32_16x16x32_bf16(a2h[kt], bW3h[nt][kt], acc, 0, 0, 0);
#pragma unroll
            for (int reg = 0; reg < 4; ++reg) {
                float p = silu_f(acc[reg] + bx1v[nt]);
                phiP[reg][0] += p * w20[nt];
                phiP[reg][1] += p * w21[nt];
            }
        }
#pragma unroll
        for (int reg = 0; reg < 4; ++reg) {
            phiP[reg][0] = row16_sum(phiP[reg][0]);
            phiP[reg][1] = row16_sum(phiP[reg][1]);
        }
        if (m == 0) {
#pragma unroll
            for (int reg = 0; reg < 4; ++reg) {
                int il = 16 * wv + 4 * q + reg;
                *(float2*)&u.run.Phi[il][0] = make_float2(phiP[reg][0], phiP[reg][1]);
            }
        }
        if (q == 0) {
            float2 ph = *(const float2*)&u.run.Phi[rowA][0];
            float f0 = ph.x * ik0;
            float f1 = ph.y * ik1;
            accX[0] += f0 * d0; accX[1] += f0 * d1; accX[2] += f0 * d2;
            accX[3] += f1 * d3; accX[4] += f1 * d4; accX[5] += f1 * d5;
        }
    }

    // ---- final reductions: aggP cross-row shfl; accX DPP row-sum ----
#pragma unroll
    for (int nt = 0; nt < 4; ++nt) {
        aggP[nt] += __shfl_xor(aggP[nt], 16, 64);
        aggP[nt] += __shfl_xor(aggP[nt], 32, 64);
    }
#pragma unroll
    for (int c = 0; c < 6; ++c) accX[c] = row16_sum(accX[c]);
    if (q == 0) {
#pragma unroll
        for (int nt = 0; nt < 4; ++nt) u.run.Agg[wv][nt * 16 + m] = aggP[nt];
        if (m == 0) {
#pragma unroll
            for (int c = 0; c < 6; ++c) u.run.XupW[wv][c] = accX[c];
        }
    }
    __syncthreads();

    // ---- fused node update tail ----
    float xup = 0.f;
    if (tid < 64) {
        u.run.aggF[tid] = u.run.Agg[0][tid] + u.run.Agg[1][tid] +
                          u.run.Agg[2][tid] + u.run.Agg[3][tid];
        u.run.hr[tid] = h[r * HD + tid];
    }
    __syncthreads();
    if (tid < 64) {
        int j = tid;
        const float* w1 = wh1 + (size_t)l * 128 * HD;
        float acc = bh1[l * HD + j];
#pragma unroll
        for (int i = 0; i < HD; ++i) acc += u.run.hr[i] * w1[i * HD + j];
#pragma unroll
        for (int i = 0; i < HD; ++i) acc += u.run.aggF[i] * w1[(HD + i) * HD + j];
        u.run.su[j] = silu_f(acc);
    }
    __syncthreads();
    if (tid < 64) {
        int j = tid;
        const float* wq = wh2 + (size_t)l * HD * HD;
        float v = 0.f;
#pragma unroll
        for (int i = 0; i < HD; ++i) v += u.run.su[i] * wq[i * HD + j];
        float hn = u.run.hr[j] + v + bh2[l * HD + j];
        h[r * HD + j] = hn;
        u.run.h2[j] = hn;
    }
    if (tid < 6) {
        xup = u.run.XupW[0][tid] + u.run.XupW[1][tid] +
              u.run.XupW[2][tid] + u.run.XupW[3][tid];
    }
    __syncthreads();
    if (!last) {
        if (tid < 64) {
            int j = tid;
            const float* w = we1 + (size_t)(l + 1) * 130 * HD;
            float a = be1[(l + 1) * HD + j], b = 0.f;
#pragma unroll
            for (int i = 0; i < HD; ++i) {
                a += u.run.h2[i] * w[i * HD + j];
                b += u.run.h2[i] * w[(HD + i) * HD + j];
            }
            A_out[r * HD + j] = a;
            Bv_out[r * HD + j] = b;
        }
        if (tid < 6) {
            xv_out[r * 6 + tid] = xr[tid] + xup * (1.0f / 767.0f);
        }
    } else {
        if (tid < 64) {
            int j = tid;
            float o = b_head[j];
#pragma unroll
            for (int i = 0; i < HD; ++i) o += u.run.h2[i] * w_head[i * OUTD + j];
            out[TN * 6 + r * OUTD + j] = o;
        }
        if (tid < 6) {
            float xv = xr[tid] + xup * (1.0f / 767.0f);
            out[r * 6 + tid] = xv - pos[r * 3 + (tid % 3)];
        }
    }
}

extern "C" void kernel_launch(void* const* d_in, const int* in_sizes, int n_in,
                              void* d_out, int out_size, void* d_ws, size_t ws_size,
                              hipStream_t stream)
{
    const float* pos    = (const float*)d_in[0];
    const float* feat   = (const float*)d_in[1];
    const float* w_emb  = (const float*)d_in[2];
    const float* b_emb  = (const float*)d_in[3];
    const float* we1    = (const float*)d_in[4];
    const float* be1    = (const float*)d_in[5];
    const float* we2    = (const float*)d_in[6];
    const float* be2    = (const float*)d_in[7];
    const float* wx1    = (const float*)d_in[8];
    const float* bx1    = (const float*)d_in[9];
    const float* wx2    = (const float*)d_in[10];
    const float* wh1    = (const float*)d_in[11];
    const float* bh1    = (const float*)d_in[12];
    const float* wh2    = (const float*)d_in[13];
    const float* bh2    = (const float*)d_in[14];
    const float* w_head = (const float*)d_in[15];
    const float* b_head = (const float*)d_in[16];
    float* out = (float*)d_out;

    float* ws   = (float*)d_ws;
    float* h    = ws;                  // TN*HD
    float* xv0  = h + TN * HD;         // TN*6
    float* xv1  = xv0 + TN * 6;        // TN*6
    float* A0   = xv1 + TN * 6;        // TN*HD
    float* A1   = A0 + TN * HD;        // TN*HD
    float* Bv0  = A1 + TN * HD;        // TN*HD
    float* Bv1  = Bv0 + TN * HD;       // TN*HD

    k_embed_pre<<<TN, 64, 0, stream>>>(pos, feat, w_emb, b_emb, we1, be1,
                                       h, xv0, A0, Bv0);
    k_edge<<<TN, 256, 0, stream>>>(xv0, A0, Bv0, we1, we2, be2, wx1, bx1, wx2,
                                   wh1, bh1, wh2, bh2, be1,
                                   h, xv1, A1, Bv1,
                                   pos, w_head, b_head, out, 0, 0);
    k_edge<<<TN, 256, 0, stream>>>(xv1, A1, Bv1, we1, we2, be2, wx1, bx1, wx2,
                                   wh1, bh1, wh2, bh2, be1,
                                   h, xv0, A0, Bv0,
                                   pos, w_head, b_head, out, 1, 1);
}